// Round 16
// baseline (131.134 us; speedup 1.0000x reference)
//
#include <hip/hip_runtime.h>
#include <math.h>

#define EPS_RHO 1e-8f
#define EPS_DEN 1e-9f

constexpr int Bb = 2;
constexpr int Nn = 512;
constexpr int Cc = 1024;
constexpr int Aa = 64;
constexpr int TOK = Bb * Nn;   // 1024 tokens
constexpr int KGP = 576;       // P/Gt K: 512 ex + 64 ew (no pad)

typedef __attribute__((ext_vector_type(8))) short short8;
typedef __attribute__((ext_vector_type(4))) short short4v;
typedef __attribute__((ext_vector_type(4))) float f32x4;

// e_fn(s) = relu(sqrt(relu(s)+eps) - sqrt(relu(-s)+eps))
//         = sqrt(max(s,0)+eps) - sqrt(eps)   [>=0 always; ==0 for s<=0]
__device__ __forceinline__ float e_fn(float s) {
    const float SQE = 9.9999994e-05f;  // sqrtf(1e-8f)
    return sqrtf(fmaxf(s, 0.f) + EPS_RHO) - SQE;
}

__device__ __forceinline__ short f2bf(float x) {
    union { float f; unsigned u; } v; v.f = x;
    unsigned r = v.u + 0x7FFFu + ((v.u >> 16) & 1u);  // RNE
    return (short)(r >> 16);
}

// DPP-based wave64 sum: row_shr 1/2/4/8 then row_bcast 15/31 (all VALU pipe,
// zero LDS traffic), total lands in lane 63, readlane broadcasts to SGPR.
template<int CTRL>
__device__ __forceinline__ float dpp_add_step(float x) {
    int y = __builtin_amdgcn_update_dpp(0, __float_as_int(x), CTRL, 0xf, 0xf, true);
    return x + __int_as_float(y);
}

__device__ __forceinline__ float wave_sum64(float x) {
    x = dpp_add_step<0x111>(x);   // row_shr:1
    x = dpp_add_step<0x112>(x);   // row_shr:2
    x = dpp_add_step<0x114>(x);   // row_shr:4
    x = dpp_add_step<0x118>(x);   // row_shr:8   -> lanes 15/31/47/63 hold row sums
    x = dpp_add_step<0x142>(x);   // row_bcast:15 -> lane31=r0+r1, lane63=r2+r3
    x = dpp_add_step<0x143>(x);   // row_bcast:31 -> lane63 = total
    return __int_as_float(__builtin_amdgcn_readlane(__float_as_int(x), 63));
}

// ---------------------------------------------------------------------------
// prep: all f32->bf16 conversions in one memory-bound pass:
//   region 0: Xb = bf16(X)                         (1024*1024)
//   region 1: Wb = bf16([Wy_w;Wq;Wk])              (1152*1024)
//   region 2: Gt[b][c][512+a] = bf16(We_w[c][a])   (2*1024*64)
// ---------------------------------------------------------------------------
constexpr int PREP_N0 = 1024 * 1024;
constexpr int PREP_N1 = 1152 * 1024;
constexpr int PREP_N2 = 2 * 1024 * 64;
constexpr int PREP_TOT = PREP_N0 + PREP_N1 + PREP_N2;

__global__ __launch_bounds__(256) void prep_kernel(
    const float* __restrict__ X, const float* __restrict__ Wy_w,
    const float* __restrict__ Wq, const float* __restrict__ Wk,
    const float* __restrict__ We_w,
    short* __restrict__ Xb, short* __restrict__ Wb, short* __restrict__ Gt)
{
    int g = (blockIdx.x * 256 + threadIdx.x) * 4;
    if (g >= PREP_TOT) return;

    const float* src;
    short* dst;
    if (g < PREP_N0) {
        src = X + g;
        dst = Xb + g;
    } else if (g < PREP_N0 + PREP_N1) {
        int i2 = g - PREP_N0;
        if (i2 < 1048576)       src = Wy_w + i2;
        else if (i2 < 1114112)  src = Wq + (i2 - 1048576);
        else                    src = Wk + (i2 - 1114112);
        dst = Wb + i2;
    } else {
        int i3 = g - PREP_N0 - PREP_N1;      // 0 .. 131071
        int b = i3 >> 16;
        int r = i3 & 65535;
        int c = r >> 6, a = r & 63;
        src = We_w + (size_t)c * Aa + a;
        dst = Gt + ((size_t)(b * 1024 + c)) * KGP + 512 + a;
    }
    float4 v = *(const float4*)src;
    short4v o = { f2bf(v.x), f2bf(v.y), f2bf(v.z), f2bf(v.w) };
    *(short4v*)dst = o;
}

// ---------------------------------------------------------------------------
// mega_gemm (R7 structure — measured best): C = Xb @ Wb^T, LDS-staged bf16
// MFMA, 64x64 tile, 4 waves (each 32x32), BK=64, register prefetch.
// Routes: n<1024 -> Gt (transposed bf16), n<1088 -> qg f32, else kg f32.
// ---------------------------------------------------------------------------
__global__ __launch_bounds__(256) void mega_gemm(
    const short* __restrict__ Xb,    // [1024][1024] bf16
    const short* __restrict__ Wb,    // [1152][1024] bf16
    const float* __restrict__ Wy_b,  // [1024]
    short* __restrict__ Gt,          // [2][1024][KGP] bf16
    float* __restrict__ qg,          // [1024][64]
    float* __restrict__ kg)          // [2][512][64]
{
    constexpr int K = 1024, BK = 64;
    __shared__ short As[64][72];
    __shared__ short Bs[64][72];

    int tid = threadIdx.x;
    int bm = blockIdx.y * 64;
    int bn = blockIdx.x * 64;      // 0..1151
    int row = tid >> 2;            // 0..63
    int kq  = (tid & 3) << 4;      // 0,16,32,48

    const short* ag = Xb + (size_t)(bm + row) * K + kq;
    const short* bg = Wb + (size_t)(bn + row) * K + kq;

    short8 ar[2], br[2];
    ar[0] = *(const short8*)ag;       ar[1] = *(const short8*)(ag + 8);
    br[0] = *(const short8*)bg;       br[1] = *(const short8*)(bg + 8);

    int wid = tid >> 6, lane = tid & 63;
    int wm = (wid & 1) * 32, wn = (wid >> 1) * 32;
    int fr = lane & 15, fk = (lane >> 4) * 8;

    f32x4 acc[2][2] = {};

    for (int step = 0; step < K / BK; ++step) {
        __syncthreads();
        *(short8*)&As[row][kq]     = ar[0];
        *(short8*)&As[row][kq + 8] = ar[1];
        *(short8*)&Bs[row][kq]     = br[0];
        *(short8*)&Bs[row][kq + 8] = br[1];
        __syncthreads();

        if (step + 1 < K / BK) {
            const short* ag2 = ag + (size_t)(step + 1) * BK;
            const short* bg2 = bg + (size_t)(step + 1) * BK;
            ar[0] = *(const short8*)ag2;  ar[1] = *(const short8*)(ag2 + 8);
            br[0] = *(const short8*)bg2;  br[1] = *(const short8*)(bg2 + 8);
        }

        #pragma unroll
        for (int kk = 0; kk < 2; ++kk) {
            short8 af[2], bfr[2];
            #pragma unroll
            for (int mi = 0; mi < 2; ++mi)
                af[mi] = *(const short8*)&As[wm + mi * 16 + fr][kk * 32 + fk];
            #pragma unroll
            for (int ni = 0; ni < 2; ++ni)
                bfr[ni] = *(const short8*)&Bs[wn + ni * 16 + fr][kk * 32 + fk];
            #pragma unroll
            for (int mi = 0; mi < 2; ++mi)
                #pragma unroll
                for (int ni = 0; ni < 2; ++ni)
                    acc[mi][ni] = __builtin_amdgcn_mfma_f32_16x16x32_bf16(
                        af[mi], bfr[ni], acc[mi][ni], 0, 0, 0);
        }
    }

    // C/D layout: col = lane&15, row = (lane>>4)*4 + reg
    int cr = (lane >> 4) * 4;
    int cc = lane & 15;
    if (bn < 1024) {
        #pragma unroll
        for (int mi = 0; mi < 2; ++mi)
            #pragma unroll
            for (int ni = 0; ni < 2; ++ni) {
                int c = bn + wn + ni * 16 + cc;
                float bv = Wy_b[c];
                #pragma unroll
                for (int r_ = 0; r_ < 4; ++r_) {
                    int t = bm + wm + mi * 16 + cr + r_;
                    int b = t >> 9, j = t & 511;
                    Gt[((size_t)(b * 1024 + c)) * KGP + j] = f2bf(acc[mi][ni][r_] + bv);
                }
            }
    } else if (bn == 1024) {
        #pragma unroll
        for (int mi = 0; mi < 2; ++mi)
            #pragma unroll
            for (int ni = 0; ni < 2; ++ni) {
                int a = wn + ni * 16 + cc;
                #pragma unroll
                for (int r_ = 0; r_ < 4; ++r_) {
                    int t = bm + wm + mi * 16 + cr + r_;
                    qg[(size_t)t * Aa + a] = acc[mi][ni][r_];
                }
            }
    } else {
        #pragma unroll
        for (int mi = 0; mi < 2; ++mi)
            #pragma unroll
            for (int ni = 0; ni < 2; ++ni) {
                int a = wn + ni * 16 + cc;
                #pragma unroll
                for (int r_ = 0; r_ < 4; ++r_) {
                    int t = bm + wm + mi * 16 + cr + r_;
                    int b = t >> 9, j = t & 511;
                    kg[((size_t)(b * 512 + j)) * Aa + a] = acc[mi][ni][r_];
                }
            }
    }
}

// ---------------------------------------------------------------------------
// attn1_dpp: lane = a, wave walks its 128 j's serially.  Per j:
//   - coalesced 256B load kg[j][0..63] (one float per lane)
//   - e = e_fn(q[a]+k); score = wave_sum64(wphi[a]*e)  [DPP, VALU-only]
//   - ex = exp2(s*log2e) (wave-uniform); ew[a] += ex*e  (ONE accumulator reg)
//   - ex packed into per-lane reg by predicated select; stored 64-at-a-time
// NO LDS in hot loop (1.1 KB total), ~35 VGPR, 8-deep k prefetch ->
// full occupancy; removes the E-tile transpose entirely.
// exp without max-subtraction (softmax shift-invariant; scores bounded).
// ---------------------------------------------------------------------------
__global__ __launch_bounds__(256) void attn1_dpp(
    const float* __restrict__ qg,    // [1024][64]
    const float* __restrict__ kg,    // [2][512][64]
    const float* __restrict__ Wphi,  // [64]
    short* __restrict__ P,           // [1024][KGP] bf16
    float* __restrict__ denomg)      // [1024]
{
    __shared__ float ewp[4][64];
    __shared__ float dred[4];

    int t = blockIdx.x, b = t >> 9;
    int tid = threadIdx.x, w = tid >> 6, lane = tid & 63;

    const float* krow = kg + ((size_t)(b * 512 + w * 128)) * Aa + lane;
    float qa = qg[(size_t)t * Aa + lane];
    float wa = Wphi[lane];

    float kbuf[8];
    #pragma unroll
    for (int p = 0; p < 8; ++p) kbuf[p] = krow[(size_t)p * Aa];

    float ew = 0.f, dsum = 0.f;

    #pragma unroll
    for (int g = 0; g < 2; ++g) {
        float exreg = 0.f;
        for (int jb = 0; jb < 8; ++jb) {          // 8 batches x 8 j = 64 j
            #pragma unroll
            for (int u = 0; u < 8; ++u) {
                int j = g * 64 + jb * 8 + u;      // 0..127
                float kv = kbuf[u];               // static reg index
                if (j + 8 < 128)
                    kbuf[u] = krow[(size_t)(j + 8) * Aa];
                float e = e_fn(qa + kv);
                float ss = wave_sum64(wa * e);
                float ex = exp2f(ss * 1.44269504089f);
                if (lane == (j & 63)) exreg = ex; // predicated select (no branch)
                dsum += ex;                       // wave-uniform accumulate
                ew = fmaf(ex, e, ew);
            }
        }
        P[(size_t)t * KGP + w * 128 + g * 64 + lane] = f2bf(exreg);
    }

    ewp[w][lane] = ew;
    if (lane == 0) dred[w] = dsum;
    __syncthreads();

    if (tid < Aa) {
        float e4 = ewp[0][tid] + ewp[1][tid] + ewp[2][tid] + ewp[3][tid];
        P[(size_t)t * KGP + 512 + tid] = f2bf(e4);
    }
    if (tid == 0) denomg[t] = dred[0] + dred[1] + dred[2] + dred[3];
}

// ---------------------------------------------------------------------------
// attn2_gemm (R7 structure — measured best): out = (P @ Gt^T + We_b*dn)/(dn+e)
// NT bf16 MFMA GEMM, M=1024, N=1024, K=576, LDS-staged, register prefetch.
// ---------------------------------------------------------------------------
__global__ __launch_bounds__(256) void attn2_gemm(
    const short* __restrict__ P,      // [1024][KGP] bf16
    const short* __restrict__ Gt,     // [2][1024][KGP] bf16
    const float* __restrict__ We_b,   // [1024]
    const float* __restrict__ denomg, // [1024]
    float* __restrict__ out)          // [1024][1024]
{
    constexpr int BK = 64, NSTEP = KGP / BK;   // 9
    __shared__ short As[64][72];
    __shared__ short Bs[64][72];

    int tid = threadIdx.x;
    int bm = blockIdx.y * 64, bn = blockIdx.x * 64;
    int b = bm >> 9;
    int row = tid >> 2;
    int kq  = (tid & 3) << 4;

    const short* ap = P  + (size_t)(bm + row) * KGP + kq;
    const short* bp = Gt + ((size_t)(b * 1024 + bn + row)) * KGP + kq;

    short8 ar[2], br[2];
    ar[0] = *(const short8*)ap;       ar[1] = *(const short8*)(ap + 8);
    br[0] = *(const short8*)bp;       br[1] = *(const short8*)(bp + 8);

    int wid = tid >> 6, lane = tid & 63;
    int wm = (wid & 1) * 32, wn = (wid >> 1) * 32;
    int fr = lane & 15, fk = (lane >> 4) * 8;

    f32x4 acc[2][2] = {};

    for (int step = 0; step < NSTEP; ++step) {
        __syncthreads();
        *(short8*)&As[row][kq]     = ar[0];
        *(short8*)&As[row][kq + 8] = ar[1];
        *(short8*)&Bs[row][kq]     = br[0];
        *(short8*)&Bs[row][kq + 8] = br[1];
        __syncthreads();

        if (step + 1 < NSTEP) {
            const short* ap2 = ap + (size_t)(step + 1) * BK;
            const short* bp2 = bp + (size_t)(step + 1) * BK;
            ar[0] = *(const short8*)ap2;  ar[1] = *(const short8*)(ap2 + 8);
            br[0] = *(const short8*)bp2;  br[1] = *(const short8*)(bp2 + 8);
        }

        #pragma unroll
        for (int kk = 0; kk < 2; ++kk) {
            short8 af[2], bfr[2];
            #pragma unroll
            for (int mi = 0; mi < 2; ++mi)
                af[mi] = *(const short8*)&As[wm + mi * 16 + fr][kk * 32 + fk];
            #pragma unroll
            for (int ni = 0; ni < 2; ++ni)
                bfr[ni] = *(const short8*)&Bs[wn + ni * 16 + fr][kk * 32 + fk];
            #pragma unroll
            for (int mi = 0; mi < 2; ++mi)
                #pragma unroll
                for (int ni = 0; ni < 2; ++ni)
                    acc[mi][ni] = __builtin_amdgcn_mfma_f32_16x16x32_bf16(
                        af[mi], bfr[ni], acc[mi][ni], 0, 0, 0);
        }
    }

    int cr = (lane >> 4) * 4;
    int cc = lane & 15;
    #pragma unroll
    for (int mi = 0; mi < 2; ++mi)
        #pragma unroll
        for (int ni = 0; ni < 2; ++ni) {
            int c = bn + wn + ni * 16 + cc;
            float bv = We_b[c];
            #pragma unroll
            for (int r_ = 0; r_ < 4; ++r_) {
                int t = bm + wm + mi * 16 + cr + r_;
                float dn = denomg[t];
                out[(size_t)t * Cc + c] = (acc[mi][ni][r_] + bv * dn) / (dn + EPS_DEN);
            }
        }
}

// ---------------------------------------------------------------------------
extern "C" void kernel_launch(void* const* d_in, const int* in_sizes, int n_in,
                              void* d_out, int out_size, void* d_ws, size_t ws_size,
                              hipStream_t stream)
{
    const float* X    = (const float*)d_in[0];
    const float* Wq   = (const float*)d_in[1];
    const float* Wk   = (const float*)d_in[2];
    const float* Wphi = (const float*)d_in[3];
    const float* Wy_w = (const float*)d_in[4];
    const float* Wy_b = (const float*)d_in[5];
    const float* We_w = (const float*)d_in[6];
    const float* We_b = (const float*)d_in[7];
    float* out = (float*)d_out;

    float* ws = (float*)d_ws;
    float* qg     = ws;                                   // 1024*64 f32
    float* kg     = qg + (size_t)TOK * Aa;                // 2*512*64 f32
    float* denomg = kg + (size_t)TOK * Aa;                // 1024 f32
    short* Xb     = (short*)(denomg + 1024);              // 1024*1024 bf16
    short* Wb     = Xb + (size_t)1024 * 1024;             // 1152*1024 bf16
    short* Gt     = Wb + (size_t)1152 * 1024;             // 2*1024*KGP bf16
    short* P      = Gt + (size_t)2 * 1024 * KGP;          // 1024*KGP bf16

    prep_kernel<<<(PREP_TOT / 4 + 255) / 256, 256, 0, stream>>>(
        X, Wy_w, Wq, Wk, We_w, Xb, Wb, Gt);

    dim3 gg(18, 16);
    mega_gemm<<<gg, 256, 0, stream>>>(Xb, Wb, Wy_b, Gt, qg, kg);

    attn1_dpp<<<TOK, 256, 0, stream>>>(qg, kg, Wphi, P, denomg);

    dim3 g2(16, 16);
    attn2_gemm<<<g2, 256, 0, stream>>>(P, Gt, We_b, denomg, out);
}